// Round 6
// baseline (1322.368 us; speedup 1.0000x reference)
//
#include <hip/hip_runtime.h>
#include <hip/hip_bf16.h>

#define NN 3072
#define FIN 512
#define FOUT 256

typedef __attribute__((ext_vector_type(8))) short short8;
typedef __attribute__((ext_vector_type(4))) float f32x4;

__device__ __forceinline__ short f2bf(float f) {
  union { float f; unsigned u; } v; v.f = f;
  unsigned r = v.u + 0x7fffu + ((v.u >> 16) & 1u);  // RNE
  return (short)(r >> 16);
}

__device__ __forceinline__ void glds16(const short* g, short* l) {
  __builtin_amdgcn_global_load_lds(
      (const __attribute__((address_space(1))) unsigned*)g,
      (__attribute__((address_space(3))) unsigned*)l, 16, 0, 0);
}

template<int N> __device__ __forceinline__ void wait_vm() {
  if constexpr (N == 0) asm volatile("s_waitcnt vmcnt(0)" ::: "memory");
  else                  asm volatile("s_waitcnt vmcnt(8)" ::: "memory");
}

// ---------------- prep kernels (unchanged, verified) ----------------

__global__ __launch_bounds__(256) void prep_adj(const float* __restrict__ adj,
    short* __restrict__ adjbf, float2* __restrict__ dinv, const float* __restrict__ hptr)
{
  int m = blockIdx.x;
  int tid = threadIdx.x;
  const float4* row = (const float4*)(adj + (size_t)m * NN);
  short4* obf = (short4*)(adjbf + (size_t)m * NN);
  float sum = 0.f;
#pragma unroll
  for (int i = 0; i < NN / 4 / 256; ++i) {
    int idx = i * 256 + tid;
    float4 v = row[idx];
    sum += (v.x + v.y) + (v.z + v.w);
    obf[idx] = make_short4(f2bf(v.x), f2bf(v.y), f2bf(v.z), f2bf(v.w));
  }
#pragma unroll
  for (int off = 32; off > 0; off >>= 1) sum += __shfl_down(sum, off, 64);
  __shared__ float red[4];
  if ((tid & 63) == 0) red[tid >> 6] = sum;
  __syncthreads();
  if (tid == 0) {
    float s = red[0] + red[1] + red[2] + red[3];
    float h = hptr[0];
    float r = h * (1.f - s);
    float den = r * r + 1.f;
    dinv[m] = make_float2(r / den, -1.f / den);
  }
}

__global__ __launch_bounds__(256) void prep_x(const float* __restrict__ x, short* __restrict__ xbf) {
  int idx = blockIdx.x * 256 + threadIdx.x;
  float4 v = ((const float4*)x)[idx];
  ((short4*)xbf)[idx] = make_short4(f2bf(v.x), f2bf(v.y), f2bf(v.z), f2bf(v.w));
}

__global__ __launch_bounds__(256) void prep_w(const float* __restrict__ w0,
    const float* __restrict__ wr, const float* __restrict__ wi, short* __restrict__ wpack)
{
  int idx = blockIdx.x * 256 + threadIdx.x;   // [1280][512]
  int f = idx & 511;
  int i = idx >> 9;
  float v;
  if (i < 1024) {
    int j = (i < 512) ? 1 : 0;
    int local = i & 511;
    int c = local >> 1;
    const float* src = (local & 1) ? wi : wr;
    v = src[((size_t)j * FIN + f) * FOUT + c];
  } else {
    v = w0[(size_t)f * FOUT + (i - 1024)];
  }
  wpack[idx] = f2bf(v);
}

// ---------------- split-K GEMM: 128x128 tile, double-buffered, counted vmcnt ----------------
// 4 waves (2x2 of 64x64, MR=NR=4). LDS 64KB (2 blocks/CU). BK=64.
// Grid 1D: 24 j-columns x (itiles*sk); xcd = bid&7 owns 3 contiguous j-columns
// so its 3 B-panels (~2.4MB) stay L2-resident.
// sk>1: every block writes its f32 tile to partial[z]; last finisher (fence +
// atomic counter, round-4-verified) sums all slabs and runs the fused epilogue.
__global__ __launch_bounds__(256, 2) void gemm_sk(
    const short* __restrict__ Apan, int lda,
    const short* __restrict__ Badj, int ldb,
    int itiles, int sk, int kper, int mode,
    const float* __restrict__ Vin,
    const float* __restrict__ Yin,
    float* __restrict__ Fout,
    short* __restrict__ Bout,
    float* __restrict__ partial,
    int* __restrict__ cnt,
    const float2* __restrict__ dinv,
    const float* __restrict__ hptr)
{
  constexpr int BK = 64;
  const size_t SLAB = (size_t)1024 * NN;

  __shared__ short As[2][128 * BK];
  __shared__ short Bs[2][128 * BK];
  __shared__ int s_ord;

  const int tid  = threadIdx.x;
  const int lane = tid & 63;
  const int w    = tid >> 6;
  const int l15  = lane & 15;
  const int wrow = w >> 1, wcol = w & 1;

  // XCD-clustered decode (24 j-columns = 8 XCD x 3)
  const int f    = blockIdx.x;
  const int xcd  = f & 7;
  const int s    = f >> 3;
  const int perj = itiles * sk;
  const int jt   = xcd * 3 + s / perj;
  const int rr   = s % perj;
  const int it   = rr % itiles;
  const int z    = rr / itiles;

  const int i0 = it * 128;
  const int j0 = jt * 128;
  const int kbase = z * kper;
  const int NT = kper / BK;

  const int srow = lane >> 3;                 // 0..7
  const int scol = ((lane & 7) ^ srow) * 8;   // source chunk XOR-swizzle (verified r2/r5)

  const short* aSrc = Apan + (size_t)i0 * lda + kbase;
  const short* bSrc = Badj + (size_t)j0 * ldb + kbase;

  auto STAGE = [&](int t) {
    const int k0 = t * BK;
    short* at = As[t & 1];
    short* bt = Bs[t & 1];
#pragma unroll
    for (int li = 0; li < 4; ++li) {
      int rb = (w + li * 4) * 8;
      glds16(aSrc + (size_t)(rb + srow) * lda + k0 + scol, at + rb * BK);
    }
#pragma unroll
    for (int li = 0; li < 4; ++li) {
      int rb = (w + li * 4) * 8;
      glds16(bSrc + (size_t)(rb + srow) * ldb + k0 + scol, bt + rb * BK);
    }
  };

  f32x4 acc[4][4];
#pragma unroll
  for (int a = 0; a < 4; a++)
#pragma unroll
    for (int b = 0; b < 4; b++) acc[a][b] = (f32x4){0.f, 0.f, 0.f, 0.f};

  STAGE(0);
  STAGE(1);

  for (int t = 0; t < NT; ++t) {
    if (t < NT - 1) wait_vm<8>(); else wait_vm<0>();
    __builtin_amdgcn_s_barrier();
    asm volatile("" ::: "memory");

    const short* at = As[t & 1];
    const short* bt = Bs[t & 1];
#pragma unroll
    for (int kk = 0; kk < 2; ++kk) {
      const int cb = kk * 4 + (lane >> 4);
      short8 af[4], bfr[4];
#pragma unroll
      for (int a = 0; a < 4; ++a) {
        int ra = wrow * 64 + a * 16 + l15;
        int c = cb ^ (ra & 7);
        af[a] = *(const short8*)(at + ra * BK + c * 8);
      }
#pragma unroll
      for (int b = 0; b < 4; ++b) {
        int rb = wcol * 64 + b * 16 + l15;
        int c = cb ^ (rb & 7);
        bfr[b] = *(const short8*)(bt + rb * BK + c * 8);
      }
#pragma unroll
      for (int a = 0; a < 4; ++a)
#pragma unroll
        for (int b = 0; b < 4; ++b)
          acc[a][b] = __builtin_amdgcn_mfma_f32_16x16x32_bf16(af[a], bfr[b], acc[a][b], 0, 0, 0);
    }

    asm volatile("" ::: "memory");
    __builtin_amdgcn_s_barrier();
    asm volatile("" ::: "memory");
    if (t + 2 < NT) STAGE(t + 2);
  }

  const int ibase = i0 + wrow * 64 + ((lane >> 4) << 2);
  const int tile = jt * itiles + it;

  if (sk > 1) {
    float* ps = partial + (size_t)z * SLAB;
#pragma unroll
    for (int a = 0; a < 4; ++a) {
      int ia = ibase + a * 16;
#pragma unroll
      for (int b = 0; b < 4; ++b) {
        int jb = j0 + wcol * 64 + b * 16 + l15;
#pragma unroll
        for (int q = 0; q < 4; ++q)
          ps[(size_t)(ia + q) * NN + jb] = acc[a][b][q];
      }
    }
    __threadfence();
    __syncthreads();
    if (tid == 0) s_ord = atomicAdd(&cnt[tile], 1);
    __syncthreads();
    if (s_ord != sk - 1) return;     // not last: partial written, exit
    __threadfence();                 // last: acquire others' partials
  }

  const float hv = hptr[0];
#pragma unroll
  for (int a = 0; a < 4; ++a) {
    int ia = ibase + a * 16;
#pragma unroll
    for (int b = 0; b < 4; ++b) {
      int jb = j0 + wcol * 64 + b * 16 + l15;
      f32x4 c = acc[a][b];
      if (sk > 1) {
        for (int z2 = 0; z2 < sk; ++z2) {
          if (z2 == z) continue;
          const float* ps = partial + (size_t)z2 * SLAB;
#pragma unroll
          for (int q = 0; q < 4; ++q)
            c[q] += ps[(size_t)(ia + q) * NN + jb];
        }
      }
      if (mode == 0) {
#pragma unroll
        for (int q = 0; q < 4; ++q) {
          size_t off = (size_t)(ia + q) * NN + jb;
          Fout[off] = c[q];
          if (ia + q < 1024) Bout[off] = f2bf(c[q]);
        }
      } else if (mode == 1) {
#pragma unroll
        for (int p = 0; p < 4; p += 2) {
          size_t offr = (size_t)(ia + p) * NN + jb;
          size_t offi = offr + NN;
          float vr = Vin[offr], vi = Vin[offi];
          float outr = hv * (vr - c[p])     + vi;
          float outi = hv * (vi - c[p + 1]) - vr;
          Fout[offr] = outr; Fout[offi] = outi;
          Bout[offr] = f2bf(outr); Bout[offi] = f2bf(outi);
        }
      } else {
#pragma unroll
        for (int p = 0; p < 4; p += 2) {
          size_t offr = (size_t)(ia + p) * NN + jb;
          size_t offi = offr + NN;
          float2 dv = dinv[jb];
          float vr = Vin[offr], vi = Vin[offi];
          float yr = Yin[offr], yi = Yin[offi];
          float tr_ = hv * (yr - c[p])     - yi;
          float ti_ = hv * (yi - c[p + 1]) + yr;
          float er = vr - tr_, ei = vi - ti_;
          float nyr = yr + dv.x * er - dv.y * ei;
          float nyi = yi + dv.x * ei + dv.y * er;
          Fout[offr] = nyr; Fout[offi] = nyi;
          Bout[offr] = f2bf(nyr); Bout[offi] = f2bf(nyi);
        }
      }
    }
  }
}

// ---------------- final: out[node][c] = relu(out0T[c][node] + 2*(term1 + term2)) ----------------
__global__ __launch_bounds__(256) void final_out(
    const float* __restrict__ Vbuf,
    const float* __restrict__ ybuf,
    float* __restrict__ out)
{
  __shared__ float t[64][65];
  int n0 = blockIdx.x * 64;
  int c0 = blockIdx.y * 64;
  int lane = threadIdx.x & 63;
  int wv = threadIdx.x >> 6;
#pragma unroll
  for (int s = 0; s < 16; s++) {
    int c = c0 + wv + s * 4;
    float o0 = Vbuf[(size_t)(1024 + c) * NN + n0 + lane];
    float u  = ybuf[(size_t)(2 * c) * NN + n0 + lane];
    float sv = ybuf[(size_t)(512 + 2 * c) * NN + n0 + lane];
    float v = o0 + 2.f * (u + sv);
    t[lane][wv + s * 4] = v > 0.f ? v : 0.f;
  }
  __syncthreads();
#pragma unroll
  for (int s = 0; s < 16; s++) {
    int nl = wv + s * 4;
    out[(size_t)(n0 + nl) * FOUT + c0 + lane] = t[nl][lane];
  }
}

extern "C" void kernel_launch(void* const* d_in, const int* in_sizes, int n_in,
                              void* d_out, int out_size, void* d_ws, size_t ws_size,
                              hipStream_t stream) {
  const float* x   = (const float*)d_in[0];
  const float* adj = (const float*)d_in[1];
  const float* h   = (const float*)d_in[2];
  const float* w0  = (const float*)d_in[3];
  const float* wr  = (const float*)d_in[4];
  const float* wi  = (const float*)d_in[5];
  float* out = (float*)d_out;

  char* ws = (char*)d_ws;
  size_t off = 0;
  auto alloc = [&](size_t bytes) {
    char* p = ws + off;
    off += (bytes + 255) & ~(size_t)255;
    return p;
  };
  short*  adjbf = (short*)alloc((size_t)NN * NN * 2);
  short*  xbf   = (short*)alloc((size_t)NN * FIN * 2);
  short*  wpack = (short*)alloc((size_t)1280 * FIN * 2);
  float2* dinv  = (float2*)alloc((size_t)NN * sizeof(float2));
  float*  Vbuf  = (float*)alloc((size_t)1280 * NN * 4);
  float*  ybuf  = (float*)alloc((size_t)1024 * NN * 4);
  short*  b0    = (short*)alloc((size_t)1024 * NN * 2);
  short*  b1    = (short*)alloc((size_t)1024 * NN * 2);

  // split-K selection by available workspace (slab = 1024 x 3072 f32)
  size_t slab = (size_t)1024 * NN * 4;
  size_t cntB = 9 * 256 * sizeof(int);
  int sk = 1;
  if (ws_size >= off + 4 * slab + cntB + 4096) sk = 4;
  else if (ws_size >= off + 2 * slab + cntB + 4096) sk = 2;
  float* partial = (float*)alloc((size_t)sk * slab);
  int*   cnt     = (int*)alloc(cntB);

  hipMemsetAsync(cnt, 0, cntB, stream);
  prep_adj<<<NN, 256, 0, stream>>>(adj, adjbf, dinv, h);
  prep_x<<<(NN * FIN / 4) / 256, 256, 0, stream>>>(x, xbf);
  prep_w<<<(1280 * FIN) / 256, 256, 0, stream>>>(w0, wr, wi, wpack);

  auto G = [&](int itiles, int skv, int kper, int mode,
               const short* A, int lda, const short* B, int ldb,
               const float* Vin, const float* Yin, float* Fout, short* Bout, int didx) {
    gemm_sk<<<dim3(24 * itiles * skv), 256, 0, stream>>>(
        A, lda, B, ldb, itiles, skv, kper, mode,
        Vin, Yin, Fout, Bout, partial, cnt + didx * 256, dinv, h);
  };

  // GEMM0: [1280][3072] = wpack @ xbf^T, K=512 -> Vbuf (P1|P0|out0T), b0 bf16
  G(10, 1, FIN, 0, wpack, FIN, xbf, FIN, nullptr, nullptr, Vbuf, b0, 0);
  // wide A (rows 0-1023): V' = A([P1;P0]), in-place Vbuf
  G(8, sk, NN / sk, 1, b0, NN, adjbf, NN, Vbuf, nullptr, Vbuf, b1, 1);
  // wide G x3
  G(8, sk, NN / sk, 2, b1, NN, adjbf, NN, Vbuf, Vbuf, ybuf, b0, 2);
  G(8, sk, NN / sk, 2, b0, NN, adjbf, NN, Vbuf, ybuf, ybuf, b1, 3);
  G(8, sk, NN / sk, 2, b1, NN, adjbf, NN, Vbuf, ybuf, ybuf, b0, 4);
  // narrow A (chain-1 rows 0-511): input = ybuf rows 0-511, out -> Vbuf rows 0-511
  G(4, sk, NN / sk, 1, b0, NN, adjbf, NN, ybuf, nullptr, Vbuf, b1, 5);
  // narrow G x3
  G(4, sk, NN / sk, 2, b1, NN, adjbf, NN, Vbuf, Vbuf, ybuf, b0, 6);
  G(4, sk, NN / sk, 2, b0, NN, adjbf, NN, Vbuf, ybuf, ybuf, b1, 7);
  G(4, sk, NN / sk, 2, b1, NN, adjbf, NN, Vbuf, ybuf, ybuf, b0, 8);

  final_out<<<dim3(48, 4), 256, 0, stream>>>(Vbuf, ybuf, out);
}

// Round 7
// 381.909 us; speedup vs baseline: 3.4625x; 3.4625x over previous
//
#include <hip/hip_runtime.h>
#include <hip/hip_bf16.h>

#define NN 3072
#define FIN 512
#define FOUT 256

typedef __attribute__((ext_vector_type(8))) short short8;
typedef __attribute__((ext_vector_type(4))) float f32x4;

__device__ __forceinline__ short f2bf(float f) {
  union { float f; unsigned u; } v; v.f = f;
  unsigned r = v.u + 0x7fffu + ((v.u >> 16) & 1u);  // RNE
  return (short)(r >> 16);
}

__device__ __forceinline__ void glds16(const short* g, short* l) {
  __builtin_amdgcn_global_load_lds(
      (const __attribute__((address_space(1))) unsigned*)g,
      (__attribute__((address_space(3))) unsigned*)l, 16, 0, 0);
}

template<int N> __device__ __forceinline__ void wait_vm() {
  if constexpr (N == 0) asm volatile("s_waitcnt vmcnt(0)" ::: "memory");
  else                  asm volatile("s_waitcnt vmcnt(4)" ::: "memory");
}

// ---------------- prep kernels (unchanged, verified) ----------------

__global__ __launch_bounds__(256) void prep_adj(const float* __restrict__ adj,
    short* __restrict__ adjbf, float2* __restrict__ dinv, const float* __restrict__ hptr)
{
  int m = blockIdx.x;
  int tid = threadIdx.x;
  const float4* row = (const float4*)(adj + (size_t)m * NN);
  short4* obf = (short4*)(adjbf + (size_t)m * NN);
  float sum = 0.f;
#pragma unroll
  for (int i = 0; i < NN / 4 / 256; ++i) {
    int idx = i * 256 + tid;
    float4 v = row[idx];
    sum += (v.x + v.y) + (v.z + v.w);
    obf[idx] = make_short4(f2bf(v.x), f2bf(v.y), f2bf(v.z), f2bf(v.w));
  }
#pragma unroll
  for (int off = 32; off > 0; off >>= 1) sum += __shfl_down(sum, off, 64);
  __shared__ float red[4];
  if ((tid & 63) == 0) red[tid >> 6] = sum;
  __syncthreads();
  if (tid == 0) {
    float s = red[0] + red[1] + red[2] + red[3];
    float h = hptr[0];
    float r = h * (1.f - s);
    float den = r * r + 1.f;
    dinv[m] = make_float2(r / den, -1.f / den);
  }
}

__global__ __launch_bounds__(256) void prep_x(const float* __restrict__ x, short* __restrict__ xbf) {
  int idx = blockIdx.x * 256 + threadIdx.x;
  float4 v = ((const float4*)x)[idx];
  ((short4*)xbf)[idx] = make_short4(f2bf(v.x), f2bf(v.y), f2bf(v.z), f2bf(v.w));
}

__global__ __launch_bounds__(256) void prep_w(const float* __restrict__ w0,
    const float* __restrict__ wr, const float* __restrict__ wi, short* __restrict__ wpack)
{
  int idx = blockIdx.x * 256 + threadIdx.x;   // [1280][512]
  int f = idx & 511;
  int i = idx >> 9;
  float v;
  if (i < 1024) {
    int j = (i < 512) ? 1 : 0;
    int local = i & 511;
    int c = local >> 1;
    const float* src = (local & 1) ? wi : wr;
    v = src[((size_t)j * FIN + f) * FOUT + c];
  } else {
    v = w0[(size_t)f * FOUT + (i - 1024)];
  }
  wpack[idx] = f2bf(v);
}

// ---------------- 64x64-tile GEMM, double-buffered, counted vmcnt, no split-K ----------------
// 4 waves (2x2 of 32x32, MR=NR=2, acc=16 VGPR). BK=64. LDS 32KB.
// Grid 1D = 48 jtiles x ITILES: xcd = bid&7 owns 6 contiguous j-columns
// (B slice 6*64*3072*2B = 2.25MB -> L2-resident). 768 blocks wide = 3/CU
// co-resident: 3 independent barrier groups per CU overlap each other's
// stage/drain stalls (m97 mechanism).
template<int MODE, int KTOT, int ITILES>
__global__ __launch_bounds__(256, 4) void gemm_t(
    const short* __restrict__ Apan, int lda,
    const short* __restrict__ Badj, int ldb,
    const float* __restrict__ Vin,
    const float* __restrict__ Yin,
    float* __restrict__ Fout,
    short* __restrict__ Bout,
    const float2* __restrict__ dinv,
    const float* __restrict__ hptr)
{
  constexpr int BK = 64;
  constexpr int NT = KTOT / BK;

  __shared__ short As[2][64 * BK];
  __shared__ short Bs[2][64 * BK];

  const int tid  = threadIdx.x;
  const int lane = tid & 63;
  const int w    = tid >> 6;
  const int l15  = lane & 15;
  const int wrow = w >> 1, wcol = w & 1;

  // XCD-clustered decode: 8 XCDs x 6 j-columns x ITILES
  const int bid = blockIdx.x;
  const int xcd = bid & 7;
  const int s   = bid >> 3;
  const int jt  = xcd * 6 + s / ITILES;
  const int it  = s % ITILES;

  const int i0 = it * 64;
  const int j0 = jt * 64;

  const int srow = lane >> 3;                 // 0..7
  const int scol = ((lane & 7) ^ srow) * 8;   // source chunk XOR-swizzle (verified r2/r5)

  const short* aSrc = Apan + (size_t)i0 * lda;
  const short* bSrc = Badj + (size_t)j0 * ldb;

  auto STAGE = [&](int t) {
    const int k0 = t * BK;
    short* at = As[t & 1];
    short* bt = Bs[t & 1];
#pragma unroll
    for (int li = 0; li < 2; ++li) {
      int rb = (w * 2 + li) * 8;
      glds16(aSrc + (size_t)(rb + srow) * lda + k0 + scol, at + rb * BK);
    }
#pragma unroll
    for (int li = 0; li < 2; ++li) {
      int rb = (w * 2 + li) * 8;
      glds16(bSrc + (size_t)(rb + srow) * ldb + k0 + scol, bt + rb * BK);
    }
  };

  f32x4 acc[2][2];
#pragma unroll
  for (int a = 0; a < 2; a++)
#pragma unroll
    for (int b = 0; b < 2; b++) acc[a][b] = (f32x4){0.f, 0.f, 0.f, 0.f};

  STAGE(0);
  STAGE(1);

  for (int t = 0; t < NT; ++t) {
    if (t < NT - 1) wait_vm<4>(); else wait_vm<0>();
    __builtin_amdgcn_s_barrier();
    asm volatile("" ::: "memory");

    const short* at = As[t & 1];
    const short* bt = Bs[t & 1];
#pragma unroll
    for (int kk = 0; kk < 2; ++kk) {
      const int cb = kk * 4 + (lane >> 4);
      short8 af[2], bfr[2];
#pragma unroll
      for (int a = 0; a < 2; ++a) {
        int ra = wrow * 32 + a * 16 + l15;
        int c = cb ^ (ra & 7);
        af[a] = *(const short8*)(at + ra * BK + c * 8);
      }
#pragma unroll
      for (int b = 0; b < 2; ++b) {
        int rb = wcol * 32 + b * 16 + l15;
        int c = cb ^ (rb & 7);
        bfr[b] = *(const short8*)(bt + rb * BK + c * 8);
      }
      __builtin_amdgcn_s_setprio(1);
#pragma unroll
      for (int a = 0; a < 2; ++a)
#pragma unroll
        for (int b = 0; b < 2; ++b)
          acc[a][b] = __builtin_amdgcn_mfma_f32_16x16x32_bf16(af[a], bfr[b], acc[a][b], 0, 0, 0);
      __builtin_amdgcn_s_setprio(0);
    }

    asm volatile("" ::: "memory");
    __builtin_amdgcn_s_barrier();
    asm volatile("" ::: "memory");
    if (t + 2 < NT) STAGE(t + 2);
  }

  const float hv = hptr[0];
  const int ibase = i0 + wrow * 32 + ((lane >> 4) << 2);
#pragma unroll
  for (int a = 0; a < 2; ++a) {
    const int ia = ibase + a * 16;
#pragma unroll
    for (int b = 0; b < 2; ++b) {
      const int jb = j0 + wcol * 32 + b * 16 + l15;
      f32x4 c = acc[a][b];
      if (MODE == 0) {
#pragma unroll
        for (int q = 0; q < 4; ++q) {
          size_t off = (size_t)(ia + q) * NN + jb;
          Fout[off] = c[q];
          if (ia + q < 1024) Bout[off] = f2bf(c[q]);
        }
      } else if (MODE == 1) {
#pragma unroll
        for (int p = 0; p < 4; p += 2) {
          size_t offr = (size_t)(ia + p) * NN + jb;
          size_t offi = offr + NN;
          float vr = Vin[offr], vi = Vin[offi];
          float outr = hv * (vr - c[p])     + vi;
          float outi = hv * (vi - c[p + 1]) - vr;
          Fout[offr] = outr; Fout[offi] = outi;
          Bout[offr] = f2bf(outr); Bout[offi] = f2bf(outi);
        }
      } else {
#pragma unroll
        for (int p = 0; p < 4; p += 2) {
          size_t offr = (size_t)(ia + p) * NN + jb;
          size_t offi = offr + NN;
          float2 dv = dinv[jb];
          float vr = Vin[offr], vi = Vin[offi];
          float yr = Yin[offr], yi = Yin[offi];
          float tr_ = hv * (yr - c[p])     - yi;
          float ti_ = hv * (yi - c[p + 1]) + yr;
          float er = vr - tr_, ei = vi - ti_;
          float nyr = yr + dv.x * er - dv.y * ei;
          float nyi = yi + dv.x * ei + dv.y * er;
          Fout[offr] = nyr; Fout[offi] = nyi;
          Bout[offr] = f2bf(nyr); Bout[offi] = f2bf(nyi);
        }
      }
    }
  }
}

// ---------------- final: out[node][c] = relu(out0T[c][node] + 2*(term1 + term2)) ----------------
__global__ __launch_bounds__(256) void final_out(
    const float* __restrict__ Vbuf,
    const float* __restrict__ ybuf,
    float* __restrict__ out)
{
  __shared__ float t[64][65];
  int n0 = blockIdx.x * 64;
  int c0 = blockIdx.y * 64;
  int lane = threadIdx.x & 63;
  int wv = threadIdx.x >> 6;
#pragma unroll
  for (int s = 0; s < 16; s++) {
    int c = c0 + wv + s * 4;
    float o0 = Vbuf[(size_t)(1024 + c) * NN + n0 + lane];
    float u  = ybuf[(size_t)(2 * c) * NN + n0 + lane];
    float sv = ybuf[(size_t)(512 + 2 * c) * NN + n0 + lane];
    float v = o0 + 2.f * (u + sv);
    t[lane][wv + s * 4] = v > 0.f ? v : 0.f;
  }
  __syncthreads();
#pragma unroll
  for (int s = 0; s < 16; s++) {
    int nl = wv + s * 4;
    out[(size_t)(n0 + nl) * FOUT + c0 + lane] = t[nl][lane];
  }
}

extern "C" void kernel_launch(void* const* d_in, const int* in_sizes, int n_in,
                              void* d_out, int out_size, void* d_ws, size_t ws_size,
                              hipStream_t stream) {
  const float* x   = (const float*)d_in[0];
  const float* adj = (const float*)d_in[1];
  const float* h   = (const float*)d_in[2];
  const float* w0  = (const float*)d_in[3];
  const float* wr  = (const float*)d_in[4];
  const float* wi  = (const float*)d_in[5];
  float* out = (float*)d_out;

  char* ws = (char*)d_ws;
  size_t off = 0;
  auto alloc = [&](size_t bytes) {
    char* p = ws + off;
    off += (bytes + 255) & ~(size_t)255;
    return p;
  };
  short*  adjbf = (short*)alloc((size_t)NN * NN * 2);
  short*  xbf   = (short*)alloc((size_t)NN * FIN * 2);
  short*  wpack = (short*)alloc((size_t)1280 * FIN * 2);
  float2* dinv  = (float2*)alloc((size_t)NN * sizeof(float2));
  float*  Vbuf  = (float*)alloc((size_t)1280 * NN * 4);
  float*  ybuf  = (float*)alloc((size_t)1024 * NN * 4);
  short*  b0    = (short*)alloc((size_t)1024 * NN * 2);
  short*  b1    = (short*)alloc((size_t)1024 * NN * 2);

  prep_adj<<<NN, 256, 0, stream>>>(adj, adjbf, dinv, h);
  prep_x<<<(NN * FIN / 4) / 256, 256, 0, stream>>>(x, xbf);
  prep_w<<<(1280 * FIN) / 256, 256, 0, stream>>>(w0, wr, wi, wpack);

  // GEMM0: [1280][3072] = wpack @ xbf^T, K=512 -> Vbuf (P1|P0|out0T), b0 bf16
  gemm_t<0, FIN, 20><<<dim3(48 * 20), 256, 0, stream>>>(
      wpack, FIN, xbf, FIN, nullptr, nullptr, Vbuf, b0, dinv, h);
  // wide A (rows 0-1023): V' = A([P1;P0]), in-place Vbuf
  gemm_t<1, NN, 16><<<dim3(48 * 16), 256, 0, stream>>>(
      b0, NN, adjbf, NN, Vbuf, nullptr, Vbuf, b1, dinv, h);
  // wide G x3
  gemm_t<2, NN, 16><<<dim3(48 * 16), 256, 0, stream>>>(
      b1, NN, adjbf, NN, Vbuf, Vbuf, ybuf, b0, dinv, h);
  gemm_t<2, NN, 16><<<dim3(48 * 16), 256, 0, stream>>>(
      b0, NN, adjbf, NN, Vbuf, ybuf, ybuf, b1, dinv, h);
  gemm_t<2, NN, 16><<<dim3(48 * 16), 256, 0, stream>>>(
      b1, NN, adjbf, NN, Vbuf, ybuf, ybuf, b0, dinv, h);
  // narrow A (chain-1 rows 0-511): input = ybuf rows 0-511, out -> Vbuf rows 0-511
  gemm_t<1, NN, 8><<<dim3(48 * 8), 256, 0, stream>>>(
      b0, NN, adjbf, NN, ybuf, nullptr, Vbuf, b1, dinv, h);
  // narrow G x3
  gemm_t<2, NN, 8><<<dim3(48 * 8), 256, 0, stream>>>(
      b1, NN, adjbf, NN, Vbuf, Vbuf, ybuf, b0, dinv, h);
  gemm_t<2, NN, 8><<<dim3(48 * 8), 256, 0, stream>>>(
      b0, NN, adjbf, NN, Vbuf, ybuf, ybuf, b1, dinv, h);
  gemm_t<2, NN, 8><<<dim3(48 * 8), 256, 0, stream>>>(
      b1, NN, adjbf, NN, Vbuf, ybuf, ybuf, b0, dinv, h);

  final_out<<<dim3(48, 4), 256, 0, stream>>>(Vbuf, ybuf, out);
}

// Round 8
// 362.029 us; speedup vs baseline: 3.6527x; 1.0549x over previous
//
#include <hip/hip_runtime.h>
#include <hip/hip_bf16.h>

#define NN 3072
#define FIN 512
#define FOUT 256

typedef __attribute__((ext_vector_type(8))) short short8;
typedef __attribute__((ext_vector_type(4))) float f32x4;

__device__ __forceinline__ short f2bf(float f) {
  union { float f; unsigned u; } v; v.f = f;
  unsigned r = v.u + 0x7fffu + ((v.u >> 16) & 1u);  // RNE
  return (short)(r >> 16);
}

__device__ __forceinline__ void glds16(const short* g, short* l) {
  __builtin_amdgcn_global_load_lds(
      (const __attribute__((address_space(1))) unsigned*)g,
      (__attribute__((address_space(3))) unsigned*)l, 16, 0, 0);
}

template<int N> __device__ __forceinline__ void wait_vm() {
  if constexpr (N == 0)      asm volatile("s_waitcnt vmcnt(0)" ::: "memory");
  else if constexpr (N == 5) asm volatile("s_waitcnt vmcnt(5)" ::: "memory");
  else                       asm volatile("s_waitcnt vmcnt(7)" ::: "memory");
}

// ---------------- prep kernels ----------------

__global__ __launch_bounds__(256) void prep_adj(const float* __restrict__ adj,
    short* __restrict__ adjbf, float2* __restrict__ dinv, const float* __restrict__ hptr)
{
  int m = blockIdx.x;
  int tid = threadIdx.x;
  const float4* row = (const float4*)(adj + (size_t)m * NN);
  short4* obf = (short4*)(adjbf + (size_t)m * NN);
  float sum = 0.f;
#pragma unroll
  for (int i = 0; i < NN / 4 / 256; ++i) {
    int idx = i * 256 + tid;
    float4 v = row[idx];
    sum += (v.x + v.y) + (v.z + v.w);
    obf[idx] = make_short4(f2bf(v.x), f2bf(v.y), f2bf(v.z), f2bf(v.w));
  }
#pragma unroll
  for (int off = 32; off > 0; off >>= 1) sum += __shfl_down(sum, off, 64);
  __shared__ float red[4];
  if ((tid & 63) == 0) red[tid >> 6] = sum;
  __syncthreads();
  if (tid == 0) {
    float s = red[0] + red[1] + red[2] + red[3];
    float h = hptr[0];
    float r = h * (1.f - s);
    float den = r * r + 1.f;
    dinv[m] = make_float2(r / den, -1.f / den);
  }
}

// merged prep_x (blocks 0..1535, short4 over x) + prep_w (blocks 1536..4095)
__global__ __launch_bounds__(256) void prep_xw(const float* __restrict__ x,
    const float* __restrict__ w0, const float* __restrict__ wr,
    const float* __restrict__ wi, short* __restrict__ xbf, short* __restrict__ wpack)
{
  int b = blockIdx.x;
  if (b < 1536) {
    int idx = b * 256 + threadIdx.x;
    float4 v = ((const float4*)x)[idx];
    ((short4*)xbf)[idx] = make_short4(f2bf(v.x), f2bf(v.y), f2bf(v.z), f2bf(v.w));
  } else {
    int idx = (b - 1536) * 256 + threadIdx.x;   // [1280][512]
    int f = idx & 511;
    int i = idx >> 9;
    float v;
    if (i < 1024) {
      int j = (i < 512) ? 1 : 0;
      int local = i & 511;
      int c = local >> 1;
      const float* src = (local & 1) ? wi : wr;
      v = src[((size_t)j * FIN + f) * FOUT + c];
    } else {
      v = w0[(size_t)f * FOUT + (i - 1024)];
    }
    wpack[idx] = f2bf(v);
  }
}

// ---------------- GEMM: BMx96 tile, in-block split-K x2, double-buffered ----------------
// 512 threads = 8 waves = 2 K-groups x 4 spatial (2x2). Per-wave out (BM/2)x48,
// MR = BM/32, NR = 3. BK=64, per-group double-buffered LDS, counted vmcnt
// (depth-2: stage(t+1) in flight during compute(t)). XOR chunk swizzle
// (verified r2/r5/r7). K-group g covers k in [g*KTOT/2, ...). LDS reduction
// (r2-verified) then fused epilogue by group 0.
// Grid 1D = 8 xcd * 4 jt * itiles; 32 j-columns of 96 -> 4 per XCD (B slice
// ~2.4MB L2-resident).
template<int BM, int MODE, int KTOT>
__global__ __launch_bounds__(512, 2) void gemm_g(
    const short* __restrict__ Apan, int lda,
    const short* __restrict__ Badj, int ldb,
    int itiles,
    const float* __restrict__ Vin,
    const float* __restrict__ Yin,
    float* __restrict__ Fout,
    short* __restrict__ Bout,
    const float2* __restrict__ dinv,
    const float* __restrict__ hptr)
{
  constexpr int BK = 64;
  constexpr int BN = 96;
  constexpr int NT = KTOT / 2 / BK;
  constexpr int MR = BM / 32;      // also A stage-issues per wave
  constexpr int LPW = MR + 3;      // + 3 B stage-issues per wave

  __shared__ short As[2][2][BM * BK];
  __shared__ short Bs[2][2][BN * BK];

  const int tid  = threadIdx.x;
  const int lane = tid & 63;
  const int w    = tid >> 6;
  const int g    = w >> 2;          // K-split group
  const int wg   = w & 3;           // spatial wave
  const int l15  = lane & 15;
  const int wrow = wg >> 1, wcol = wg & 1;

  const int bid = blockIdx.x;
  const int xcd = bid & 7;
  const int s   = bid >> 3;
  const int jt  = xcd * 4 + s / itiles;
  const int it  = s % itiles;
  const int i0  = it * BM;
  const int j0  = jt * BN;

  const int srow = lane >> 3;                 // 0..7
  const int scol = ((lane & 7) ^ srow) * 8;   // source chunk XOR-swizzle

  const short* aSrc = Apan + (size_t)i0 * lda + g * (KTOT / 2);
  const short* bSrc = Badj + (size_t)j0 * ldb + g * (KTOT / 2);

  auto STAGE = [&](int t) {
    const int k0 = t * BK;
    short* at = As[g][t & 1];
    short* bt = Bs[g][t & 1];
#pragma unroll
    for (int li = 0; li < MR; ++li) {
      int rb = (wg + li * 4) * 8;
      glds16(aSrc + (size_t)(rb + srow) * lda + k0 + scol, at + rb * BK);
    }
#pragma unroll
    for (int li = 0; li < 3; ++li) {
      int rb = (wg + li * 4) * 8;
      glds16(bSrc + (size_t)(rb + srow) * ldb + k0 + scol, bt + rb * BK);
    }
  };

  f32x4 acc[MR][3];
#pragma unroll
  for (int a = 0; a < MR; a++)
#pragma unroll
    for (int b = 0; b < 3; b++) acc[a][b] = (f32x4){0.f, 0.f, 0.f, 0.f};

  STAGE(0);
  STAGE(1);

  for (int t = 0; t < NT; ++t) {
    if (t < NT - 1) wait_vm<LPW>(); else wait_vm<0>();
    __builtin_amdgcn_s_barrier();
    asm volatile("" ::: "memory");

    const short* at = As[g][t & 1];
    const short* bt = Bs[g][t & 1];
#pragma unroll
    for (int kk = 0; kk < 2; ++kk) {
      const int cb = kk * 4 + (lane >> 4);
      short8 af[MR], bfr[3];
#pragma unroll
      for (int a = 0; a < MR; ++a) {
        int ra = wrow * (BM / 2) + a * 16 + l15;
        int c = cb ^ (ra & 7);
        af[a] = *(const short8*)(at + ra * BK + c * 8);
      }
#pragma unroll
      for (int b = 0; b < 3; ++b) {
        int rb = wcol * 48 + b * 16 + l15;
        int c = cb ^ (rb & 7);
        bfr[b] = *(const short8*)(bt + rb * BK + c * 8);
      }
      __builtin_amdgcn_s_setprio(1);
#pragma unroll
      for (int a = 0; a < MR; ++a)
#pragma unroll
        for (int b = 0; b < 3; ++b)
          acc[a][b] = __builtin_amdgcn_mfma_f32_16x16x32_bf16(af[a], bfr[b], acc[a][b], 0, 0, 0);
      __builtin_amdgcn_s_setprio(0);
    }

    asm volatile("" ::: "memory");
    __builtin_amdgcn_s_barrier();
    asm volatile("" ::: "memory");
    if (t + 2 < NT) STAGE(t + 2);
  }

  // ---- in-block split-K reduction (r2-verified), f32 scratch reuses As ----
  float* red = (float*)&As[0][0][0];   // BM x 96 f32 (fits: BM*384 <= BM*512 B)
  const int rl0 = wrow * (BM / 2) + ((lane >> 4) << 2);
  const int cl0 = wcol * 48 + l15;
  if (g == 1) {
#pragma unroll
    for (int a = 0; a < MR; ++a)
#pragma unroll
      for (int b = 0; b < 3; ++b)
#pragma unroll
        for (int q = 0; q < 4; ++q)
          red[(size_t)(rl0 + a * 16 + q) * BN + cl0 + b * 16] = acc[a][b][q];
  }
  __syncthreads();
  if (g == 1) return;

  const float hv = hptr[0];
#pragma unroll
  for (int a = 0; a < MR; ++a) {
    const int rl = rl0 + a * 16;
    const int ia = i0 + rl;
#pragma unroll
    for (int b = 0; b < 3; ++b) {
      const int cl = cl0 + b * 16;
      const int jb = j0 + cl;
      f32x4 c = acc[a][b];
#pragma unroll
      for (int q = 0; q < 4; ++q)
        c[q] += red[(size_t)(rl + q) * BN + cl];
      if (MODE == 0) {
#pragma unroll
        for (int q = 0; q < 4; ++q) {
          size_t off = (size_t)(ia + q) * NN + jb;
          Fout[off] = c[q];
          if (ia + q < 1024) Bout[off] = f2bf(c[q]);
        }
      } else if (MODE == 1) {
#pragma unroll
        for (int p = 0; p < 4; p += 2) {
          size_t offr = (size_t)(ia + p) * NN + jb;
          size_t offi = offr + NN;
          float vr = Vin[offr], vi = Vin[offi];
          float outr = hv * (vr - c[p])     + vi;
          float outi = hv * (vi - c[p + 1]) - vr;
          Fout[offr] = outr; Fout[offi] = outi;
          Bout[offr] = f2bf(outr); Bout[offi] = f2bf(outi);
        }
      } else {
#pragma unroll
        for (int p = 0; p < 4; p += 2) {
          size_t offr = (size_t)(ia + p) * NN + jb;
          size_t offi = offr + NN;
          float2 dv = dinv[jb];
          float vr = Vin[offr], vi = Vin[offi];
          float yr = Yin[offr], yi = Yin[offi];
          float tr_ = hv * (yr - c[p])     - yi;
          float ti_ = hv * (yi - c[p + 1]) + yr;
          float er = vr - tr_, ei = vi - ti_;
          float nyr = yr + dv.x * er - dv.y * ei;
          float nyi = yi + dv.x * ei + dv.y * er;
          Fout[offr] = nyr; Fout[offi] = nyi;
          Bout[offr] = f2bf(nyr); Bout[offi] = f2bf(nyi);
        }
      }
    }
  }
}

// ---------------- final: out[node][c] = relu(out0T[c][node] + 2*(term1 + term2)) ----------------
__global__ __launch_bounds__(256) void final_out(
    const float* __restrict__ Vbuf,
    const float* __restrict__ ybuf,
    float* __restrict__ out)
{
  __shared__ float t[64][65];
  int n0 = blockIdx.x * 64;
  int c0 = blockIdx.y * 64;
  int lane = threadIdx.x & 63;
  int wv = threadIdx.x >> 6;
#pragma unroll
  for (int s = 0; s < 16; s++) {
    int c = c0 + wv + s * 4;
    float o0 = Vbuf[(size_t)(1024 + c) * NN + n0 + lane];
    float u  = ybuf[(size_t)(2 * c) * NN + n0 + lane];
    float sv = ybuf[(size_t)(512 + 2 * c) * NN + n0 + lane];
    float v = o0 + 2.f * (u + sv);
    t[lane][wv + s * 4] = v > 0.f ? v : 0.f;
  }
  __syncthreads();
#pragma unroll
  for (int s = 0; s < 16; s++) {
    int nl = wv + s * 4;
    out[(size_t)(n0 + nl) * FOUT + c0 + lane] = t[nl][lane];
  }
}

extern "C" void kernel_launch(void* const* d_in, const int* in_sizes, int n_in,
                              void* d_out, int out_size, void* d_ws, size_t ws_size,
                              hipStream_t stream) {
  const float* x   = (const float*)d_in[0];
  const float* adj = (const float*)d_in[1];
  const float* h   = (const float*)d_in[2];
  const float* w0  = (const float*)d_in[3];
  const float* wr  = (const float*)d_in[4];
  const float* wi  = (const float*)d_in[5];
  float* out = (float*)d_out;

  char* ws = (char*)d_ws;
  size_t off = 0;
  auto alloc = [&](size_t bytes) {
    char* p = ws + off;
    off += (bytes + 255) & ~(size_t)255;
    return p;
  };
  short*  adjbf = (short*)alloc((size_t)NN * NN * 2);
  short*  xbf   = (short*)alloc((size_t)NN * FIN * 2);
  short*  wpack = (short*)alloc((size_t)1280 * FIN * 2);
  float2* dinv  = (float2*)alloc((size_t)NN * sizeof(float2));
  float*  Vbuf  = (float*)alloc((size_t)1280 * NN * 4);
  float*  ybuf  = (float*)alloc((size_t)1024 * NN * 4);
  short*  b0    = (short*)alloc((size_t)1024 * NN * 2);
  short*  b1    = (short*)alloc((size_t)1024 * NN * 2);

  prep_adj<<<NN, 256, 0, stream>>>(adj, adjbf, dinv, h);
  prep_xw<<<4096, 256, 0, stream>>>(x, w0, wr, wi, xbf, wpack);

  // GEMM0: [1280][3072] = wpack @ xbf^T, K=512 -> Vbuf (P1|P0|out0T), b0 bf16
  gemm_g<128, 0, FIN><<<dim3(32 * 10), 512, 0, stream>>>(
      wpack, FIN, xbf, FIN, 10, nullptr, nullptr, Vbuf, b0, dinv, h);
  // wide A (rows 0-1023): V' = A([P1;P0]), in-place Vbuf
  gemm_g<128, 1, NN><<<dim3(32 * 8), 512, 0, stream>>>(
      b0, NN, adjbf, NN, 8, Vbuf, nullptr, Vbuf, b1, dinv, h);
  // wide G x3
  gemm_g<128, 2, NN><<<dim3(32 * 8), 512, 0, stream>>>(
      b1, NN, adjbf, NN, 8, Vbuf, Vbuf, ybuf, b0, dinv, h);
  gemm_g<128, 2, NN><<<dim3(32 * 8), 512, 0, stream>>>(
      b0, NN, adjbf, NN, 8, Vbuf, ybuf, ybuf, b1, dinv, h);
  gemm_g<128, 2, NN><<<dim3(32 * 8), 512, 0, stream>>>(
      b1, NN, adjbf, NN, 8, Vbuf, ybuf, ybuf, b0, dinv, h);
  // narrow A (chain-1 rows 0-511): input = ybuf rows 0-511, out -> Vbuf rows 0-511
  gemm_g<64, 1, NN><<<dim3(32 * 8), 512, 0, stream>>>(
      b0, NN, adjbf, NN, 8, ybuf, nullptr, Vbuf, b1, dinv, h);
  // narrow G x3
  gemm_g<64, 2, NN><<<dim3(32 * 8), 512, 0, stream>>>(
      b1, NN, adjbf, NN, 8, Vbuf, Vbuf, ybuf, b0, dinv, h);
  gemm_g<64, 2, NN><<<dim3(32 * 8), 512, 0, stream>>>(
      b0, NN, adjbf, NN, 8, Vbuf, ybuf, ybuf, b1, dinv, h);
  gemm_g<64, 2, NN><<<dim3(32 * 8), 512, 0, stream>>>(
      b1, NN, adjbf, NN, 8, Vbuf, ybuf, ybuf, b0, dinv, h);

  final_out<<<dim3(48, 4), 256, 0, stream>>>(Vbuf, ybuf, out);
}